// Round 9
// baseline (637.732 us; speedup 1.0000x reference)
//
#include <hip/hip_runtime.h>
#include <hip/hip_bf16.h>

// 2-layer GraphSAGE mean-aggr, N=100000, E=1600000, F=128.
// R8: attack csr_mean (2x124us, top dispatch; 378MB HBM fetch of random row
// gather + 51.2MB/layer mean round-trip).
//   - cast x -> bf16 xb once (halves layer-1 gather bytes)
//   - layer 1 FUSED: per 64-row block, gather-mean from xb into LDS Am
//     (fp32 acc), then MFMA K-loop reads A from Am (chunks 0/1) or staged
//     own-rows of xb (chunks 2/3). No mean buffer, no mean traffic.
//   - layer 2 unfused (fusion is racy: epilogue would overwrite rows other
//     blocks gather-read): csr_mean(d_out fp32) -> mean-bf16 into xb (dead),
//     then proven sage_gemm_mfma. h stays fp32 in d_out.
//   - ws layout 32.93MB < proven 33.34MB; CSR-build transients alias into xb
//     (consumed by bucket_fill before cast writes xb).

#define N_NODES 100000
#define N_EDGES 1600000
#define F 128
#define NB 391        // ceil(N/256) scan blocks
#define NBK 782       // ceil(N/128) buckets (128 nodes each)
#define NSB 391       // scatter blocks (4096 edges each)

typedef __attribute__((ext_vector_type(8))) short short8;
typedef __attribute__((ext_vector_type(4))) float f32x4;

__device__ __forceinline__ unsigned short f2bf(float f) {
    union { __hip_bfloat16 h; unsigned short u; } cv;
    cv.h = __float2bfloat16(f);
    return cv.u;
}
__device__ __forceinline__ float bf2f(unsigned short u) {
    return __uint_as_float(((unsigned)u) << 16);
}

// ---------------- deg histogram ----------------
__global__ __launch_bounds__(256) void hist_kernel(
    const int* __restrict__ dst, int* __restrict__ deg_i, int E)
{
    int e = blockIdx.x * 256 + threadIdx.x;
    if (e < E) atomicAdd(&deg_i[dst[e]], 1);
}

// ---------------- rowptr (exclusive scan of deg) ----------------
__global__ __launch_bounds__(256) void partial_sum_kernel(
    const int* __restrict__ deg_i, int* __restrict__ partial, int N)
{
    int i = blockIdx.x * 256 + threadIdx.x;
    int d = (i < N) ? deg_i[i] : 0;
#pragma unroll
    for (int off = 32; off > 0; off >>= 1) d += __shfl_down(d, off, 64);
    __shared__ int ws[4];
    if ((threadIdx.x & 63) == 0) ws[threadIdx.x >> 6] = d;
    __syncthreads();
    if (threadIdx.x == 0) partial[blockIdx.x] = ws[0] + ws[1] + ws[2] + ws[3];
}

__global__ __launch_bounds__(512) void scan_partial_kernel(int* partial)
{
    __shared__ int s[512];
    int t = threadIdx.x;
    s[t] = (t < NB) ? partial[t] : 0;
    __syncthreads();
#pragma unroll
    for (int off = 1; off < 512; off <<= 1) {
        int v = (t >= off) ? s[t - off] : 0;
        __syncthreads();
        s[t] += v;
        __syncthreads();
    }
    partial[t] = (t == 0) ? 0 : s[t - 1];
}

__global__ __launch_bounds__(256) void rowptr_kernel(
    const int* __restrict__ deg_i, const int* __restrict__ partial,
    int* __restrict__ rowptr, int N)
{
    __shared__ int s[256];
    int t = threadIdx.x;
    int i = blockIdx.x * 256 + t;
    int d = (i < N) ? deg_i[i] : 0;
    s[t] = d;
    __syncthreads();
#pragma unroll
    for (int off = 1; off < 256; off <<= 1) {
        int v = (t >= off) ? s[t - off] : 0;
        __syncthreads();
        s[t] += v;
        __syncthreads();
    }
    if (i < N) rowptr[i] = partial[blockIdx.x] + s[t] - d;   // exclusive
}

// ---------------- contention-free bucket permute (R7-proven) ----------------
__global__ __launch_bounds__(256) void blkhist_kernel(
    const int* __restrict__ dst, int* __restrict__ blkhist, int E)
{
    __shared__ int h[NBK];
    int t = threadIdx.x, blk = blockIdx.x;
    for (int i = t; i < NBK; i += 256) h[i] = 0;
    __syncthreads();
    int base = blk * 4096;
    int end = min(base + 4096, E);
    for (int e = base + t; e < end; e += 256) atomicAdd(&h[dst[e] >> 7], 1);
    __syncthreads();
    for (int i = t; i < NBK; i += 256) blkhist[blk * NBK + i] = h[i];
}

__global__ __launch_bounds__(512) void bucket_scan_kernel(
    const int* __restrict__ blkhist, const int* __restrict__ rowptr,
    int* __restrict__ bbase)
{
    __shared__ int s[512];
    int b = blockIdx.x, t = threadIdx.x;
    int v = (t < NSB) ? blkhist[t * NBK + b] : 0;
    s[t] = v;
    __syncthreads();
#pragma unroll
    for (int off = 1; off < 512; off <<= 1) {
        int u = (t >= off) ? s[t - off] : 0;
        __syncthreads();
        s[t] += u;
        __syncthreads();
    }
    if (t < NSB) bbase[t * NBK + b] = rowptr[b << 7] + s[t] - v;
}

__global__ __launch_bounds__(256) void bucket_scatter_kernel(
    const int* __restrict__ src, const int* __restrict__ dst,
    const int* __restrict__ bbase, unsigned* __restrict__ staging, int E)
{
    __shared__ int cur[NBK];
    int t = threadIdx.x, blk = blockIdx.x;
    for (int i = t; i < NBK; i += 256) cur[i] = bbase[blk * NBK + i];
    __syncthreads();
    int base = blk * 4096;
    int end = min(base + 4096, E);
    for (int e = base + t; e < end; e += 256) {
        int d = dst[e];
        int p = atomicAdd(&cur[d >> 7], 1);
        staging[p] = ((unsigned)src[e] << 7) | (unsigned)(d & 127);
    }
}

__global__ __launch_bounds__(256) void bucket_fill_kernel(
    const unsigned* __restrict__ staging, const int* __restrict__ rowptr,
    int* __restrict__ csr_src, int N, int E)
{
    __shared__ int cur[128];
    int b = blockIdx.x;
    int base_node = b << 7;
    int t = threadIdx.x;
    if (t < 128) {
        int node = base_node + t;
        cur[t] = (node < N) ? rowptr[node] : 0;
    }
    __syncthreads();
    int start = rowptr[base_node];
    int end = (base_node + 128 < N) ? rowptr[base_node + 128] : E;
    for (int e = start + t; e < end; e += 256) {
        unsigned u = staging[e];
        int p = atomicAdd(&cur[u & 127], 1);
        csr_src[p] = (int)(u >> 7);
    }
}

// ---------------- weight transpose+cast: Wt[layer][col][k] bf16 ----------------
__global__ __launch_bounds__(256) void wt_kernel(
    const float* __restrict__ Wl1, const float* __restrict__ Wr1,
    const float* __restrict__ Wl2, const float* __restrict__ Wr2,
    unsigned short* __restrict__ wt)
{
    int e = blockIdx.x * 256 + threadIdx.x;   // 0..65535
    int layer = e >> 15;
    int idx = e & 32767;
    int k = idx >> 7;      // 0..255
    int c = idx & 127;
    const float* W = (layer == 0) ? (k < 128 ? Wl1 : Wr1)
                                  : (k < 128 ? Wl2 : Wr2);
    float v = W[(k & 127) * 128 + c];
    wt[layer * 32768 + c * 256 + k] = f2bf(v);
}

// ---------------- cast x -> bf16 ----------------
__global__ __launch_bounds__(256) void cast_kernel(
    const float* __restrict__ x, unsigned short* __restrict__ xb, int total4)
{
    int i = blockIdx.x * 256 + threadIdx.x;
    if (i >= total4) return;
    float4 v = ((const float4*)x)[i];
    unsigned lo = ((unsigned)f2bf(v.y) << 16) | f2bf(v.x);
    unsigned hi = ((unsigned)f2bf(v.w) << 16) | f2bf(v.z);
    ((uint2*)xb)[i] = make_uint2(lo, hi);
}

// ---------------- layer 2 aggregate: mean over in-neighbors (fp32 src) ----
__global__ __launch_bounds__(256) void csr_mean_kernel(
    const float* __restrict__ feat, const int* __restrict__ rowptr,
    const int* __restrict__ deg_i, const int* __restrict__ csr_src,
    unsigned int* __restrict__ mean, int N)
{
    int n = blockIdx.x * 4 + (threadIdx.x >> 6);
    int lane = threadIdx.x & 63;
    if (n >= N) return;
    int start = rowptr[n];
    int dg = deg_i[n];
    int end = start + dg;
    float ax = 0.f, ay = 0.f;
    int e = start;
    for (; e + 1 < end; e += 2) {
        int s0 = csr_src[e], s1 = csr_src[e + 1];
        float2 v0 = ((const float2*)feat)[s0 * 64 + lane];
        float2 v1 = ((const float2*)feat)[s1 * 64 + lane];
        ax += v0.x + v1.x;
        ay += v0.y + v1.y;
    }
    if (e < end) {
        int s0 = csr_src[e];
        float2 v0 = ((const float2*)feat)[s0 * 64 + lane];
        ax += v0.x;
        ay += v0.y;
    }
    float r = 1.0f / fmaxf((float)dg, 1.0f);
    mean[n * 64 + lane] = ((unsigned)f2bf(ay * r) << 16) | f2bf(ax * r);
}

// ---------------- FUSED layer 1: gather-mean (bf16 x) + MFMA GEMM ----------------
// block = 64 rows x 128 cols, 4 waves. Phase 1: each wave gather-means 16
// nodes from xb into Am (fp32 acc, bf16 store). Phase 2: K=256 MFMA loop,
// A from Am (chunks 0/1 = mean) or staged own-rows of xb (chunks 2/3 = x).
// LDS: Am 17408 + As 9216 + Bs 18432 = 45056 B -> 3 blocks/CU.
template <bool RELU>
__global__ __launch_bounds__(256) void sage_fused_mfma(
    const unsigned short* __restrict__ xb,
    const int* __restrict__ rowptr, const int* __restrict__ deg_i,
    const int* __restrict__ csr_src,
    const unsigned short* __restrict__ wt,   // [128 cols][256 k] bf16
    const float* __restrict__ bias,
    float* __restrict__ outp, int N)
{
    __shared__ unsigned short Am[64][136];   // 272B row: 16B-aligned, 2-way (free)
    __shared__ unsigned short As[64][72];
    __shared__ unsigned short Bs[128][72];

    const int t = threadIdx.x;
    const int block_row = blockIdx.x * 64;
    const int lane = t & 63;
    const int w = t >> 6;
    const int m = lane & 15;
    const int kq = lane >> 4;

    // ---- phase 1: gather-mean rows [w*16, w*16+16) ----
    for (int i = 0; i < 16; ++i) {
        int row_l = w * 16 + i;
        int n = block_row + row_l;
        float ax = 0.f, ay = 0.f;
        if (n < N) {
            int start = rowptr[n];
            int dg = deg_i[n];
            int end = start + dg;
            int e = start;
            for (; e + 1 < end; e += 2) {
                int s0 = csr_src[e], s1 = csr_src[e + 1];
                unsigned u0 = ((const unsigned*)xb)[(size_t)s0 * 64 + lane];
                unsigned u1 = ((const unsigned*)xb)[(size_t)s1 * 64 + lane];
                ax += bf2f((unsigned short)u0) + bf2f((unsigned short)u1);
                ay += bf2f((unsigned short)(u0 >> 16)) + bf2f((unsigned short)(u1 >> 16));
            }
            if (e < end) {
                int s0 = csr_src[e];
                unsigned u0 = ((const unsigned*)xb)[(size_t)s0 * 64 + lane];
                ax += bf2f((unsigned short)u0);
                ay += bf2f((unsigned short)(u0 >> 16));
            }
            float r = 1.0f / fmaxf((float)dg, 1.0f);
            ax *= r; ay *= r;
        }
        ((unsigned*)&Am[row_l][0])[lane] = ((unsigned)f2bf(ay) << 16) | f2bf(ax);
    }
    __syncthreads();

    // ---- phase 2: MFMA K-loop ----
    f32x4 acc[8];
#pragma unroll
    for (int i = 0; i < 8; ++i) acc[i] = (f32x4){0.f, 0.f, 0.f, 0.f};

    for (int chunk = 0; chunk < 4; ++chunk) {
        const bool is_mean = (chunk < 2);
        const int kbase = (chunk & 1) * 64;

        if (!is_mean) {
            // stage own x rows (bf16): each thread 16 bf16 = 32 B
            int row_l = t >> 2;
            int seg = t & 3;
            int grow = block_row + row_l;
            unsigned short* dstp = &As[row_l][seg * 16];
            if (grow < N) {
                const uint4* p = (const uint4*)(xb + (size_t)grow * F + kbase + seg * 16);
                ((uint4*)dstp)[0] = p[0];
                ((uint4*)dstp)[1] = p[1];
            } else {
                uint4 z = make_uint4(0, 0, 0, 0);
                ((uint4*)dstp)[0] = z;
                ((uint4*)dstp)[1] = z;
            }
        }
        // B tile: 128 cols x 64 k from Wt (each thread: 32 bf16 = 64 B)
        {
            int c = t >> 1;
            int half = t & 1;
            const uint4* p = (const uint4*)(wt + c * 256 + chunk * 64 + half * 32);
            unsigned short* dstp = &Bs[c][half * 32];
            ((uint4*)dstp)[0] = p[0];
            ((uint4*)dstp)[1] = p[1];
            ((uint4*)dstp)[2] = p[2];
            ((uint4*)dstp)[3] = p[3];
        }
        __syncthreads();

#pragma unroll
        for (int ks = 0; ks < 2; ++ks) {
            short8 a = is_mean
                ? *(const short8*)&Am[w * 16 + m][kbase + ks * 32 + kq * 8]
                : *(const short8*)&As[w * 16 + m][ks * 32 + kq * 8];
#pragma unroll
            for (int tt = 0; tt < 8; ++tt) {
                short8 b = *(const short8*)&Bs[tt * 16 + m][ks * 32 + kq * 8];
                acc[tt] = __builtin_amdgcn_mfma_f32_16x16x32_bf16(a, b, acc[tt], 0, 0, 0);
            }
        }
        __syncthreads();
    }

    // ---- epilogue: C/D row=(lane>>4)*4+reg, col=lane&15; h fp32 -> d_out ----
    float bb[8];
#pragma unroll
    for (int tt = 0; tt < 8; ++tt) bb[tt] = bias[tt * 16 + m];
    int rbase = block_row + w * 16 + kq * 4;
#pragma unroll
    for (int r = 0; r < 4; ++r) {
        int grow = rbase + r;
        if (grow < N) {
#pragma unroll
            for (int tt = 0; tt < 8; ++tt) {
                float v = acc[tt][r] + bb[tt];
                if (RELU) v = fmaxf(v, 0.f);
                outp[(size_t)grow * F + tt * 16 + m] = v;
            }
        }
    }
}

// ---------------- layer 2 GEMM (R4/R7-proven) ----------------
template <bool RELU>
__global__ __launch_bounds__(256) void sage_gemm_mfma(
    const unsigned short* __restrict__ meanb,
    const float* __restrict__ xin,
    const unsigned short* __restrict__ wt,
    const float* __restrict__ bias,
    float* __restrict__ outp, int N)
{
    __shared__ unsigned short As[64][72];
    __shared__ unsigned short Bs[128][72];

    const int t = threadIdx.x;
    const int block_row = blockIdx.x * 64;
    const int lane = t & 63;
    const int w = t >> 6;
    const int m = lane & 15;
    const int kq = lane >> 4;

    f32x4 acc[8];
#pragma unroll
    for (int i = 0; i < 8; ++i) acc[i] = (f32x4){0.f, 0.f, 0.f, 0.f};

    for (int chunk = 0; chunk < 4; ++chunk) {
        const bool is_mean = (chunk < 2);
        const int kbase = (chunk & 1) * 64;

        {
            int row_l = t >> 2;
            int seg = t & 3;
            int grow = block_row + row_l;
            unsigned short* dstp = &As[row_l][seg * 16];
            if (grow < N) {
                if (is_mean) {
                    const uint4* p = (const uint4*)(meanb + (size_t)grow * F + kbase + seg * 16);
                    ((uint4*)dstp)[0] = p[0];
                    ((uint4*)dstp)[1] = p[1];
                } else {
                    const float4* p = (const float4*)(xin + (size_t)grow * F + kbase + seg * 16);
#pragma unroll
                    for (int q = 0; q < 4; ++q) {
                        float4 v = p[q];
                        unsigned lo = ((unsigned)f2bf(v.y) << 16) | f2bf(v.x);
                        unsigned hi = ((unsigned)f2bf(v.w) << 16) | f2bf(v.z);
                        ((unsigned*)dstp)[q * 2]     = lo;
                        ((unsigned*)dstp)[q * 2 + 1] = hi;
                    }
                }
            } else {
                uint4 z = make_uint4(0, 0, 0, 0);
                ((uint4*)dstp)[0] = z;
                ((uint4*)dstp)[1] = z;
            }
        }
        {
            int c = t >> 1;
            int half = t & 1;
            const uint4* p = (const uint4*)(wt + c * 256 + chunk * 64 + half * 32);
            unsigned short* dstp = &Bs[c][half * 32];
            ((uint4*)dstp)[0] = p[0];
            ((uint4*)dstp)[1] = p[1];
            ((uint4*)dstp)[2] = p[2];
            ((uint4*)dstp)[3] = p[3];
        }
        __syncthreads();

#pragma unroll
        for (int ks = 0; ks < 2; ++ks) {
            short8 a = *(const short8*)&As[w * 16 + m][ks * 32 + kq * 8];
#pragma unroll
            for (int tt = 0; tt < 8; ++tt) {
                short8 b = *(const short8*)&Bs[tt * 16 + m][ks * 32 + kq * 8];
                acc[tt] = __builtin_amdgcn_mfma_f32_16x16x32_bf16(a, b, acc[tt], 0, 0, 0);
            }
        }
        __syncthreads();
    }

    float bb[8];
#pragma unroll
    for (int tt = 0; tt < 8; ++tt) bb[tt] = bias[tt * 16 + m];
    int rbase = block_row + w * 16 + kq * 4;
#pragma unroll
    for (int r = 0; r < 4; ++r) {
        int grow = rbase + r;
        if (grow < N) {
#pragma unroll
            for (int tt = 0; tt < 8; ++tt) {
                float v = acc[tt][r] + bb[tt];
                if (RELU) v = fmaxf(v, 0.f);
                outp[(size_t)grow * F + tt * 16 + m] = v;
            }
        }
    }
}

extern "C" void kernel_launch(void* const* d_in, const int* in_sizes, int n_in,
                              void* d_out, int out_size, void* d_ws, size_t ws_size,
                              hipStream_t stream) {
    const float* x    = (const float*)d_in[0];
    const int*   ei   = (const int*)d_in[1];    // int32 (harness converts int64)
    const float* W_l1 = (const float*)d_in[2];
    const float* W_r1 = (const float*)d_in[3];
    const float* b1   = (const float*)d_in[4];
    const float* W_l2 = (const float*)d_in[5];
    const float* W_r2 = (const float*)d_in[6];
    const float* b2   = (const float*)d_in[7];
    float* out        = (float*)d_out;

    const int N = N_NODES;
    const int E = N_EDGES;
    const int* srcv = ei;
    const int* dstv = ei + E;

    // ---- workspace layout (bytes); ws_size proven >= 33,337,344 ----
    const size_t rowptr_off = 400128;
    const size_t part_off   = 800256;            // 2048 B
    const size_t csr_off    = 802304;            // int[1.6M] = 6.4 MB
    const size_t xb_off     = 7202304;           // bf16[N*F] = 25.6 MB -> 32,802,304
    const size_t wt_off     = 32802304;          // bf16[2][128][256] -> 32,933,376
    const size_t need_min   = 32933376;          // < proven 33,337,344
    // transients aliased into xb region (consumed by bucket_fill before cast):
    const size_t blkh_rel   = 0;                 // int[NSB*NBK]
    const size_t bbase_rel  = 1223168;           // int[NSB*NBK]
    const size_t stag_rel   = 2446336;           // uint[1.6M] -> 8,846,336 (< 25.6MB)

    if (ws_size < need_min) return;  // clean validation failure as diagnostic

    char* ws = (char*)d_ws;
    int* deg_i   = (int*)ws;
    int* rowptr  = (int*)(ws + rowptr_off);
    int* partial = (int*)(ws + part_off);
    int* csr_src = (int*)(ws + csr_off);
    unsigned short* xb    = (unsigned short*)(ws + xb_off);
    unsigned int*   mean2u = (unsigned int*)(ws + xb_off);     // layer-2 mean reuses xb
    const unsigned short* mean2b = (const unsigned short*)(ws + xb_off);
    int* blkhist = (int*)(ws + xb_off + blkh_rel);
    int* bbase   = (int*)(ws + xb_off + bbase_rel);
    unsigned* staging = (unsigned*)(ws + xb_off + stag_rel);
    unsigned short* wt = (unsigned short*)(ws + wt_off);

    // ---- deg + rowptr ----
    hipMemsetAsync(deg_i, 0, (size_t)N * sizeof(int), stream);
    hist_kernel<<<dim3((E + 255) / 256), dim3(256), 0, stream>>>(dstv, deg_i, E);
    partial_sum_kernel<<<dim3(NB), dim3(256), 0, stream>>>(deg_i, partial, N);
    scan_partial_kernel<<<dim3(1), dim3(512), 0, stream>>>(partial);
    rowptr_kernel<<<dim3(NB), dim3(256), 0, stream>>>(deg_i, partial, rowptr, N);

    // ---- contention-free bucket permute -> csr_src ----
    blkhist_kernel<<<dim3(NSB), dim3(256), 0, stream>>>(dstv, blkhist, E);
    bucket_scan_kernel<<<dim3(NBK), dim3(512), 0, stream>>>(blkhist, rowptr, bbase);
    bucket_scatter_kernel<<<dim3(NSB), dim3(256), 0, stream>>>(
        srcv, dstv, bbase, staging, E);
    bucket_fill_kernel<<<dim3(NBK), dim3(256), 0, stream>>>(
        staging, rowptr, csr_src, N, E);

    // ---- weight prep + x cast (after staging consumed) ----
    wt_kernel<<<dim3(256), dim3(256), 0, stream>>>(W_l1, W_r1, W_l2, W_r2, wt);
    cast_kernel<<<dim3((N * F / 4 + 255) / 256), dim3(256), 0, stream>>>(x, xb, N * F / 4);

    dim3 gblock(256), ggrid((N + 63) / 64);
    dim3 ablock(256), agrid((N + 3) / 4);

    // ---- layer 1: fused gather-mean + GEMM, h fp32 -> d_out ----
    sage_fused_mfma<true><<<ggrid, gblock, 0, stream>>>(
        xb, rowptr, deg_i, csr_src, wt, b1, out, N);

    // ---- layer 2: mean(d_out fp32) -> xb (bf16), then GEMM -> d_out ----
    csr_mean_kernel<<<agrid, ablock, 0, stream>>>(out, rowptr, deg_i, csr_src, mean2u, N);
    sage_gemm_mfma<false><<<ggrid, gblock, 0, stream>>>(mean2b, out, wt + 32768, b2, out, N);
}

// Round 10
// 472.593 us; speedup vs baseline: 1.3494x; 1.3494x over previous
//
#include <hip/hip_runtime.h>
#include <hip/hip_bf16.h>

// 2-layer GraphSAGE mean-aggr, N=100000, E=1600000, F=128.
// R9: revert R8 fusion (occupancy 25% killed the latency-bound gather;
// LESSON: gather needs max waves + tiny footprint). R7 structure + bf16
// everywhere on the gather path, no new buffers:
//   - cast x -> bf16 xb once; both csr_means gather bf16 (FETCH halved,
//     8 VGPR / 0 LDS / high occupancy preserved)
//   - means stored bf16 INTERLEAVED in d_out (row i first 256B of its 512B
//     slot) -> no extra ws; gemm reads own rows' mean, writes same rows after
//   - gemm1 writes h bf16 into xb (x dead; same-block aliasing, R5 pattern)
//   - gemm2 reads mean2(d_out)+h(xb), writes fp32 d_out
// ws layout 32.93MB < proven 33.34MB; CSR transients alias into xb region
// (consumed by bucket_fill before cast writes xb).

#define N_NODES 100000
#define N_EDGES 1600000
#define F 128
#define MPITCH 256    // mean row pitch in bf16 elems (interleaved in d_out)
#define NB 391        // ceil(N/256) scan blocks
#define NBK 782       // ceil(N/128) buckets (128 nodes each)
#define NSB 391       // scatter blocks (4096 edges each)

typedef __attribute__((ext_vector_type(8))) short short8;
typedef __attribute__((ext_vector_type(4))) float f32x4;

__device__ __forceinline__ unsigned short f2bf(float f) {
    union { __hip_bfloat16 h; unsigned short u; } cv;
    cv.h = __float2bfloat16(f);
    return cv.u;
}
__device__ __forceinline__ float bf2f(unsigned short u) {
    return __uint_as_float(((unsigned)u) << 16);
}

// ---------------- deg histogram ----------------
__global__ __launch_bounds__(256) void hist_kernel(
    const int* __restrict__ dst, int* __restrict__ deg_i, int E)
{
    int e = blockIdx.x * 256 + threadIdx.x;
    if (e < E) atomicAdd(&deg_i[dst[e]], 1);
}

// ---------------- rowptr (exclusive scan of deg) ----------------
__global__ __launch_bounds__(256) void partial_sum_kernel(
    const int* __restrict__ deg_i, int* __restrict__ partial, int N)
{
    int i = blockIdx.x * 256 + threadIdx.x;
    int d = (i < N) ? deg_i[i] : 0;
#pragma unroll
    for (int off = 32; off > 0; off >>= 1) d += __shfl_down(d, off, 64);
    __shared__ int ws[4];
    if ((threadIdx.x & 63) == 0) ws[threadIdx.x >> 6] = d;
    __syncthreads();
    if (threadIdx.x == 0) partial[blockIdx.x] = ws[0] + ws[1] + ws[2] + ws[3];
}

__global__ __launch_bounds__(512) void scan_partial_kernel(int* partial)
{
    __shared__ int s[512];
    int t = threadIdx.x;
    s[t] = (t < NB) ? partial[t] : 0;
    __syncthreads();
#pragma unroll
    for (int off = 1; off < 512; off <<= 1) {
        int v = (t >= off) ? s[t - off] : 0;
        __syncthreads();
        s[t] += v;
        __syncthreads();
    }
    partial[t] = (t == 0) ? 0 : s[t - 1];
}

__global__ __launch_bounds__(256) void rowptr_kernel(
    const int* __restrict__ deg_i, const int* __restrict__ partial,
    int* __restrict__ rowptr, int N)
{
    __shared__ int s[256];
    int t = threadIdx.x;
    int i = blockIdx.x * 256 + t;
    int d = (i < N) ? deg_i[i] : 0;
    s[t] = d;
    __syncthreads();
#pragma unroll
    for (int off = 1; off < 256; off <<= 1) {
        int v = (t >= off) ? s[t - off] : 0;
        __syncthreads();
        s[t] += v;
        __syncthreads();
    }
    if (i < N) rowptr[i] = partial[blockIdx.x] + s[t] - d;   // exclusive
}

// ---------------- contention-free bucket permute (R7-proven) ----------------
__global__ __launch_bounds__(256) void blkhist_kernel(
    const int* __restrict__ dst, int* __restrict__ blkhist, int E)
{
    __shared__ int h[NBK];
    int t = threadIdx.x, blk = blockIdx.x;
    for (int i = t; i < NBK; i += 256) h[i] = 0;
    __syncthreads();
    int base = blk * 4096;
    int end = min(base + 4096, E);
    for (int e = base + t; e < end; e += 256) atomicAdd(&h[dst[e] >> 7], 1);
    __syncthreads();
    for (int i = t; i < NBK; i += 256) blkhist[blk * NBK + i] = h[i];
}

__global__ __launch_bounds__(512) void bucket_scan_kernel(
    const int* __restrict__ blkhist, const int* __restrict__ rowptr,
    int* __restrict__ bbase)
{
    __shared__ int s[512];
    int b = blockIdx.x, t = threadIdx.x;
    int v = (t < NSB) ? blkhist[t * NBK + b] : 0;
    s[t] = v;
    __syncthreads();
#pragma unroll
    for (int off = 1; off < 512; off <<= 1) {
        int u = (t >= off) ? s[t - off] : 0;
        __syncthreads();
        s[t] += u;
        __syncthreads();
    }
    if (t < NSB) bbase[t * NBK + b] = rowptr[b << 7] + s[t] - v;
}

__global__ __launch_bounds__(256) void bucket_scatter_kernel(
    const int* __restrict__ src, const int* __restrict__ dst,
    const int* __restrict__ bbase, unsigned* __restrict__ staging, int E)
{
    __shared__ int cur[NBK];
    int t = threadIdx.x, blk = blockIdx.x;
    for (int i = t; i < NBK; i += 256) cur[i] = bbase[blk * NBK + i];
    __syncthreads();
    int base = blk * 4096;
    int end = min(base + 4096, E);
    for (int e = base + t; e < end; e += 256) {
        int d = dst[e];
        int p = atomicAdd(&cur[d >> 7], 1);
        staging[p] = ((unsigned)src[e] << 7) | (unsigned)(d & 127);
    }
}

__global__ __launch_bounds__(256) void bucket_fill_kernel(
    const unsigned* __restrict__ staging, const int* __restrict__ rowptr,
    int* __restrict__ csr_src, int N, int E)
{
    __shared__ int cur[128];
    int b = blockIdx.x;
    int base_node = b << 7;
    int t = threadIdx.x;
    if (t < 128) {
        int node = base_node + t;
        cur[t] = (node < N) ? rowptr[node] : 0;
    }
    __syncthreads();
    int start = rowptr[base_node];
    int end = (base_node + 128 < N) ? rowptr[base_node + 128] : E;
    for (int e = start + t; e < end; e += 256) {
        unsigned u = staging[e];
        int p = atomicAdd(&cur[u & 127], 1);
        csr_src[p] = (int)(u >> 7);
    }
}

// ---------------- weight transpose+cast: Wt[layer][col][k] bf16 ----------------
__global__ __launch_bounds__(256) void wt_kernel(
    const float* __restrict__ Wl1, const float* __restrict__ Wr1,
    const float* __restrict__ Wl2, const float* __restrict__ Wr2,
    unsigned short* __restrict__ wt)
{
    int e = blockIdx.x * 256 + threadIdx.x;   // 0..65535
    int layer = e >> 15;
    int idx = e & 32767;
    int k = idx >> 7;      // 0..255
    int c = idx & 127;
    const float* W = (layer == 0) ? (k < 128 ? Wl1 : Wr1)
                                  : (k < 128 ? Wl2 : Wr2);
    float v = W[(k & 127) * 128 + c];
    wt[layer * 32768 + c * 256 + k] = f2bf(v);
}

// ---------------- cast x -> bf16 ----------------
__global__ __launch_bounds__(256) void cast_kernel(
    const float* __restrict__ x, unsigned short* __restrict__ xb, int total4)
{
    int i = blockIdx.x * 256 + threadIdx.x;
    if (i >= total4) return;
    float4 v = ((const float4*)x)[i];
    unsigned lo = ((unsigned)f2bf(v.y) << 16) | f2bf(v.x);
    unsigned hi = ((unsigned)f2bf(v.w) << 16) | f2bf(v.z);
    ((uint2*)xb)[i] = make_uint2(lo, hi);
}

// ---------------- aggregate: mean over in-neighbors (bf16 src) ----------------
// writes bf16 mean interleaved: row n -> meanu[n*(MPITCH/2) + lane] (256B/row)
__global__ __launch_bounds__(256) void csr_mean_kernel(
    const unsigned* __restrict__ featb, const int* __restrict__ rowptr,
    const int* __restrict__ deg_i, const int* __restrict__ csr_src,
    unsigned int* __restrict__ mean, int N)
{
    int n = blockIdx.x * 4 + (threadIdx.x >> 6);
    int lane = threadIdx.x & 63;
    if (n >= N) return;
    int start = rowptr[n];
    int dg = deg_i[n];
    int end = start + dg;
    float ax = 0.f, ay = 0.f;
    int e = start;
    for (; e + 1 < end; e += 2) {
        int s0 = csr_src[e], s1 = csr_src[e + 1];
        unsigned u0 = featb[(size_t)s0 * 64 + lane];
        unsigned u1 = featb[(size_t)s1 * 64 + lane];
        ax += bf2f((unsigned short)u0) + bf2f((unsigned short)u1);
        ay += bf2f((unsigned short)(u0 >> 16)) + bf2f((unsigned short)(u1 >> 16));
    }
    if (e < end) {
        int s0 = csr_src[e];
        unsigned u0 = featb[(size_t)s0 * 64 + lane];
        ax += bf2f((unsigned short)u0);
        ay += bf2f((unsigned short)(u0 >> 16));
    }
    float r = 1.0f / fmaxf((float)dg, 1.0f);
    mean[(size_t)n * (MPITCH / 2) + lane] = ((unsigned)f2bf(ay * r) << 16) | f2bf(ax * r);
}

// ---------------- MFMA GEMM: out = [mean|x] @ Wt^T + bias (+relu) ----------------
// 256 thr = 4 waves; block computes 64 rows x 128 cols; K=256 in 4 chunks.
// meanb: bf16, row pitch MPITCH (interleaved in d_out). xin: bf16, pitch F.
// Aliasing-safe: block reads ONLY its own rows of meanb/xin; epilogue writes
// those same rows after all reads (ordered by __syncthreads within block).
template <bool RELU, bool OUT_BF16>
__global__ __launch_bounds__(256) void sage_gemm_mfma(
    const unsigned short* __restrict__ meanb,
    const unsigned short* __restrict__ xin,
    const unsigned short* __restrict__ wt,   // [128 cols][256 k] bf16
    const float* __restrict__ bias,
    float* __restrict__ outp, unsigned short* __restrict__ outb, int N)
{
    __shared__ unsigned short As[64][72];    // stride 144 B: 16B-aligned, conflict-free b128
    __shared__ unsigned short Bs[128][72];

    const int t = threadIdx.x;
    const int block_row = blockIdx.x * 64;
    const int lane = t & 63;
    const int w = t >> 6;
    const int m = lane & 15;
    const int kq = lane >> 4;

    f32x4 acc[8];
#pragma unroll
    for (int i = 0; i < 8; ++i) acc[i] = (f32x4){0.f, 0.f, 0.f, 0.f};

    for (int chunk = 0; chunk < 4; ++chunk) {
        const bool is_mean = (chunk < 2);
        const int kbase = (chunk & 1) * 64;

        // ---- A tile: 64 rows x 64 k (each thread: 16 bf16 = 32 B) ----
        {
            int row_l = t >> 2;
            int seg = t & 3;
            int grow = block_row + row_l;
            unsigned short* dstp = &As[row_l][seg * 16];
            if (grow < N) {
                const unsigned short* srcp = is_mean
                    ? meanb + (size_t)grow * MPITCH + kbase + seg * 16
                    : xin   + (size_t)grow * F      + kbase + seg * 16;
                const uint4* p = (const uint4*)srcp;
                ((uint4*)dstp)[0] = p[0];
                ((uint4*)dstp)[1] = p[1];
            } else {
                uint4 z = make_uint4(0, 0, 0, 0);
                ((uint4*)dstp)[0] = z;
                ((uint4*)dstp)[1] = z;
            }
        }
        // ---- B tile: 128 cols x 64 k from Wt (each thread: 32 bf16 = 64 B) ----
        {
            int c = t >> 1;
            int half = t & 1;
            const uint4* p = (const uint4*)(wt + c * 256 + chunk * 64 + half * 32);
            unsigned short* dstp = &Bs[c][half * 32];
            ((uint4*)dstp)[0] = p[0];
            ((uint4*)dstp)[1] = p[1];
            ((uint4*)dstp)[2] = p[2];
            ((uint4*)dstp)[3] = p[3];
        }
        __syncthreads();

        // ---- MFMA: A[m=lane&15][k=(lane>>4)*8+j], B[k][n=lane&15] ----
#pragma unroll
        for (int ks = 0; ks < 2; ++ks) {
            short8 a = *(const short8*)&As[w * 16 + m][ks * 32 + kq * 8];
#pragma unroll
            for (int tt = 0; tt < 8; ++tt) {
                short8 b = *(const short8*)&Bs[tt * 16 + m][ks * 32 + kq * 8];
                acc[tt] = __builtin_amdgcn_mfma_f32_16x16x32_bf16(a, b, acc[tt], 0, 0, 0);
            }
        }
        __syncthreads();
    }

    // ---- epilogue: C/D row=(lane>>4)*4+reg, col=lane&15 ----
    float bb[8];
#pragma unroll
    for (int tt = 0; tt < 8; ++tt) bb[tt] = bias[tt * 16 + m];
    int rbase = block_row + w * 16 + kq * 4;
#pragma unroll
    for (int r = 0; r < 4; ++r) {
        int grow = rbase + r;
        if (grow < N) {
#pragma unroll
            for (int tt = 0; tt < 8; ++tt) {
                float v = acc[tt][r] + bb[tt];
                if (RELU) v = fmaxf(v, 0.f);
                if (OUT_BF16)
                    outb[(size_t)grow * F + tt * 16 + m] = f2bf(v);
                else
                    outp[(size_t)grow * F + tt * 16 + m] = v;
            }
        }
    }
}

extern "C" void kernel_launch(void* const* d_in, const int* in_sizes, int n_in,
                              void* d_out, int out_size, void* d_ws, size_t ws_size,
                              hipStream_t stream) {
    const float* x    = (const float*)d_in[0];
    const int*   ei   = (const int*)d_in[1];    // int32 (harness converts int64)
    const float* W_l1 = (const float*)d_in[2];
    const float* W_r1 = (const float*)d_in[3];
    const float* b1   = (const float*)d_in[4];
    const float* W_l2 = (const float*)d_in[5];
    const float* W_r2 = (const float*)d_in[6];
    const float* b2   = (const float*)d_in[7];
    float* out        = (float*)d_out;

    const int N = N_NODES;
    const int E = N_EDGES;
    const int* srcv = ei;
    const int* dstv = ei + E;

    // ---- workspace layout (bytes); ws_size proven >= 33,337,344 ----
    const size_t rowptr_off = 400128;
    const size_t part_off   = 800256;            // 2048 B
    const size_t csr_off    = 802304;            // int[1.6M] = 6.4 MB
    const size_t xb_off     = 7202304;           // bf16[N*F] = 25.6 MB -> 32,802,304
    const size_t wt_off     = 32802304;          // bf16[2][128][256] -> 32,933,376
    const size_t need_min   = 32933376;          // < proven 33,337,344
    // transients aliased into xb region (consumed by bucket_fill before cast):
    const size_t blkh_rel   = 0;                 // int[NSB*NBK]
    const size_t bbase_rel  = 1223168;           // int[NSB*NBK]
    const size_t stag_rel   = 2446336;           // uint[1.6M] -> 8,846,336 (< 25.6MB)

    if (ws_size < need_min) return;  // clean validation failure as diagnostic

    char* ws = (char*)d_ws;
    int* deg_i   = (int*)ws;
    int* rowptr  = (int*)(ws + rowptr_off);
    int* partial = (int*)(ws + part_off);
    int* csr_src = (int*)(ws + csr_off);
    unsigned short* xb = (unsigned short*)(ws + xb_off);
    int* blkhist = (int*)(ws + xb_off + blkh_rel);
    int* bbase   = (int*)(ws + xb_off + bbase_rel);
    unsigned* staging = (unsigned*)(ws + xb_off + stag_rel);
    unsigned short* wt = (unsigned short*)(ws + wt_off);
    // means live interleaved in d_out: row n -> bytes [n*512, n*512+256)
    unsigned int* meanu = (unsigned int*)d_out;
    const unsigned short* meanb = (const unsigned short*)d_out;

    // ---- deg + rowptr ----
    hipMemsetAsync(deg_i, 0, (size_t)N * sizeof(int), stream);
    hist_kernel<<<dim3((E + 255) / 256), dim3(256), 0, stream>>>(dstv, deg_i, E);
    partial_sum_kernel<<<dim3(NB), dim3(256), 0, stream>>>(deg_i, partial, N);
    scan_partial_kernel<<<dim3(1), dim3(512), 0, stream>>>(partial);
    rowptr_kernel<<<dim3(NB), dim3(256), 0, stream>>>(deg_i, partial, rowptr, N);

    // ---- contention-free bucket permute -> csr_src ----
    blkhist_kernel<<<dim3(NSB), dim3(256), 0, stream>>>(dstv, blkhist, E);
    bucket_scan_kernel<<<dim3(NBK), dim3(512), 0, stream>>>(blkhist, rowptr, bbase);
    bucket_scatter_kernel<<<dim3(NSB), dim3(256), 0, stream>>>(
        srcv, dstv, bbase, staging, E);
    bucket_fill_kernel<<<dim3(NBK), dim3(256), 0, stream>>>(
        staging, rowptr, csr_src, N, E);

    // ---- weight prep + x cast (after staging consumed) ----
    wt_kernel<<<dim3(256), dim3(256), 0, stream>>>(W_l1, W_r1, W_l2, W_r2, wt);
    cast_kernel<<<dim3((N * F / 4 + 255) / 256), dim3(256), 0, stream>>>(x, xb, N * F / 4);

    dim3 ablock(256), agrid((N + 3) / 4);
    dim3 gblock(256), ggrid((N + 63) / 64);

    // ---- layer 1: mean1(xb) -> d_out interleaved; gemm1 -> h bf16 into xb ----
    csr_mean_kernel<<<agrid, ablock, 0, stream>>>(
        (const unsigned*)xb, rowptr, deg_i, csr_src, meanu, N);
    sage_gemm_mfma<true, true><<<ggrid, gblock, 0, stream>>>(
        meanb, xb, wt, b1, nullptr, xb, N);

    // ---- layer 2: mean2(xb=h) -> d_out interleaved; gemm2 -> fp32 d_out ----
    csr_mean_kernel<<<agrid, ablock, 0, stream>>>(
        (const unsigned*)xb, rowptr, deg_i, csr_src, meanu, N);
    sage_gemm_mfma<false, false><<<ggrid, gblock, 0, stream>>>(
        meanb, xb, wt + 32768, b2, out, nullptr, N);
}

// Round 11
// 402.384 us; speedup vs baseline: 1.5849x; 1.1745x over previous
//
#include <hip/hip_runtime.h>
#include <hip/hip_bf16.h>

// 2-layer GraphSAGE mean-aggr, N=100000, E=1600000, F=128.
// R10: csr_mean is latency-bound (97us, 27% HBM, 33% VALU, 71% occ).
// Restructure gather: 1 node/wave, 4 edges per iter via quarter-waves,
// 16B/lane uint4 loads (1KB/wave/inst, unroll-2 -> 2KB in flight vs 512B
// in R9 = 4x latency tolerance). Cross-quarter shfl_xor reduce at end.
// Everything else byte-identical to R9 (single-variable experiment):
//   contention-free bucket CSR build, bf16 x/h in xb, bf16 means interleaved
//   in d_out (512B pitch), MFMA GEMMs with proven same-block aliasing.

#define N_NODES 100000
#define N_EDGES 1600000
#define F 128
#define MPITCH 256    // mean row pitch in bf16 elems (interleaved in d_out)
#define NB 391        // ceil(N/256) scan blocks
#define NBK 782       // ceil(N/128) buckets (128 nodes each)
#define NSB 391       // scatter blocks (4096 edges each)

typedef __attribute__((ext_vector_type(8))) short short8;
typedef __attribute__((ext_vector_type(4))) float f32x4;

__device__ __forceinline__ unsigned short f2bf(float f) {
    union { __hip_bfloat16 h; unsigned short u; } cv;
    cv.h = __float2bfloat16(f);
    return cv.u;
}
__device__ __forceinline__ float bf2f(unsigned short u) {
    return __uint_as_float(((unsigned)u) << 16);
}
// unpack packed bf16 pair and accumulate
__device__ __forceinline__ void upadd(unsigned u, float& a, float& b) {
    a += __uint_as_float(u << 16);
    b += __uint_as_float(u & 0xffff0000u);
}

// ---------------- deg histogram ----------------
__global__ __launch_bounds__(256) void hist_kernel(
    const int* __restrict__ dst, int* __restrict__ deg_i, int E)
{
    int e = blockIdx.x * 256 + threadIdx.x;
    if (e < E) atomicAdd(&deg_i[dst[e]], 1);
}

// ---------------- rowptr (exclusive scan of deg) ----------------
__global__ __launch_bounds__(256) void partial_sum_kernel(
    const int* __restrict__ deg_i, int* __restrict__ partial, int N)
{
    int i = blockIdx.x * 256 + threadIdx.x;
    int d = (i < N) ? deg_i[i] : 0;
#pragma unroll
    for (int off = 32; off > 0; off >>= 1) d += __shfl_down(d, off, 64);
    __shared__ int ws[4];
    if ((threadIdx.x & 63) == 0) ws[threadIdx.x >> 6] = d;
    __syncthreads();
    if (threadIdx.x == 0) partial[blockIdx.x] = ws[0] + ws[1] + ws[2] + ws[3];
}

__global__ __launch_bounds__(512) void scan_partial_kernel(int* partial)
{
    __shared__ int s[512];
    int t = threadIdx.x;
    s[t] = (t < NB) ? partial[t] : 0;
    __syncthreads();
#pragma unroll
    for (int off = 1; off < 512; off <<= 1) {
        int v = (t >= off) ? s[t - off] : 0;
        __syncthreads();
        s[t] += v;
        __syncthreads();
    }
    partial[t] = (t == 0) ? 0 : s[t - 1];
}

__global__ __launch_bounds__(256) void rowptr_kernel(
    const int* __restrict__ deg_i, const int* __restrict__ partial,
    int* __restrict__ rowptr, int N)
{
    __shared__ int s[256];
    int t = threadIdx.x;
    int i = blockIdx.x * 256 + t;
    int d = (i < N) ? deg_i[i] : 0;
    s[t] = d;
    __syncthreads();
#pragma unroll
    for (int off = 1; off < 256; off <<= 1) {
        int v = (t >= off) ? s[t - off] : 0;
        __syncthreads();
        s[t] += v;
        __syncthreads();
    }
    if (i < N) rowptr[i] = partial[blockIdx.x] + s[t] - d;   // exclusive
}

// ---------------- contention-free bucket permute (R7-proven) ----------------
__global__ __launch_bounds__(256) void blkhist_kernel(
    const int* __restrict__ dst, int* __restrict__ blkhist, int E)
{
    __shared__ int h[NBK];
    int t = threadIdx.x, blk = blockIdx.x;
    for (int i = t; i < NBK; i += 256) h[i] = 0;
    __syncthreads();
    int base = blk * 4096;
    int end = min(base + 4096, E);
    for (int e = base + t; e < end; e += 256) atomicAdd(&h[dst[e] >> 7], 1);
    __syncthreads();
    for (int i = t; i < NBK; i += 256) blkhist[blk * NBK + i] = h[i];
}

__global__ __launch_bounds__(512) void bucket_scan_kernel(
    const int* __restrict__ blkhist, const int* __restrict__ rowptr,
    int* __restrict__ bbase)
{
    __shared__ int s[512];
    int b = blockIdx.x, t = threadIdx.x;
    int v = (t < NSB) ? blkhist[t * NBK + b] : 0;
    s[t] = v;
    __syncthreads();
#pragma unroll
    for (int off = 1; off < 512; off <<= 1) {
        int u = (t >= off) ? s[t - off] : 0;
        __syncthreads();
        s[t] += u;
        __syncthreads();
    }
    if (t < NSB) bbase[t * NBK + b] = rowptr[b << 7] + s[t] - v;
}

__global__ __launch_bounds__(256) void bucket_scatter_kernel(
    const int* __restrict__ src, const int* __restrict__ dst,
    const int* __restrict__ bbase, unsigned* __restrict__ staging, int E)
{
    __shared__ int cur[NBK];
    int t = threadIdx.x, blk = blockIdx.x;
    for (int i = t; i < NBK; i += 256) cur[i] = bbase[blk * NBK + i];
    __syncthreads();
    int base = blk * 4096;
    int end = min(base + 4096, E);
    for (int e = base + t; e < end; e += 256) {
        int d = dst[e];
        int p = atomicAdd(&cur[d >> 7], 1);
        staging[p] = ((unsigned)src[e] << 7) | (unsigned)(d & 127);
    }
}

__global__ __launch_bounds__(256) void bucket_fill_kernel(
    const unsigned* __restrict__ staging, const int* __restrict__ rowptr,
    int* __restrict__ csr_src, int N, int E)
{
    __shared__ int cur[128];
    int b = blockIdx.x;
    int base_node = b << 7;
    int t = threadIdx.x;
    if (t < 128) {
        int node = base_node + t;
        cur[t] = (node < N) ? rowptr[node] : 0;
    }
    __syncthreads();
    int start = rowptr[base_node];
    int end = (base_node + 128 < N) ? rowptr[base_node + 128] : E;
    for (int e = start + t; e < end; e += 256) {
        unsigned u = staging[e];
        int p = atomicAdd(&cur[u & 127], 1);
        csr_src[p] = (int)(u >> 7);
    }
}

// ---------------- weight transpose+cast: Wt[layer][col][k] bf16 ----------------
__global__ __launch_bounds__(256) void wt_kernel(
    const float* __restrict__ Wl1, const float* __restrict__ Wr1,
    const float* __restrict__ Wl2, const float* __restrict__ Wr2,
    unsigned short* __restrict__ wt)
{
    int e = blockIdx.x * 256 + threadIdx.x;   // 0..65535
    int layer = e >> 15;
    int idx = e & 32767;
    int k = idx >> 7;      // 0..255
    int c = idx & 127;
    const float* W = (layer == 0) ? (k < 128 ? Wl1 : Wr1)
                                  : (k < 128 ? Wl2 : Wr2);
    float v = W[(k & 127) * 128 + c];
    wt[layer * 32768 + c * 256 + k] = f2bf(v);
}

// ---------------- cast x -> bf16 ----------------
__global__ __launch_bounds__(256) void cast_kernel(
    const float* __restrict__ x, unsigned short* __restrict__ xb, int total4)
{
    int i = blockIdx.x * 256 + threadIdx.x;
    if (i >= total4) return;
    float4 v = ((const float4*)x)[i];
    unsigned lo = ((unsigned)f2bf(v.y) << 16) | f2bf(v.x);
    unsigned hi = ((unsigned)f2bf(v.w) << 16) | f2bf(v.z);
    ((uint2*)xb)[i] = make_uint2(lo, hi);
}

// ---------------- aggregate: mean over in-neighbors (bf16 src) ----------------
// 1 node/wave; quarter-wave q handles edge e+q; lane c=(lane&15) loads 16B
// (8 bf16 cols) of the neighbor row. Unroll-2 -> 2KB/wave in flight.
// Final: shfl_xor(16,32) cross-quarter reduce; q==0 lanes store 16B.
// Output: bf16 mean interleaved, row pitch MPITCH (256B used per 512B slot).
__global__ __launch_bounds__(256) void csr_mean_kernel(
    const uint4* __restrict__ featb4, const int* __restrict__ rowptr,
    const int* __restrict__ deg_i, const int* __restrict__ csr_src,
    uint4* __restrict__ mean4, int N)
{
    int n = blockIdx.x * 4 + (threadIdx.x >> 6);
    int lane = threadIdx.x & 63;
    int q = lane >> 4;        // edge slot 0..3
    int c = lane & 15;        // 16B column segment
    if (n >= N) return;
    int start = rowptr[n];
    int dg = deg_i[n];
    int end = start + dg;

    float acc[8];
#pragma unroll
    for (int j = 0; j < 8; ++j) acc[j] = 0.f;

    for (int e = start; e < end; e += 8) {
        int i0 = e + q;
        int i1 = e + 4 + q;
        uint4 u0 = make_uint4(0, 0, 0, 0);
        uint4 u1 = make_uint4(0, 0, 0, 0);
        if (i0 < end) u0 = featb4[(size_t)csr_src[i0] * 16 + c];
        if (i1 < end) u1 = featb4[(size_t)csr_src[i1] * 16 + c];
        upadd(u0.x, acc[0], acc[1]);
        upadd(u0.y, acc[2], acc[3]);
        upadd(u0.z, acc[4], acc[5]);
        upadd(u0.w, acc[6], acc[7]);
        upadd(u1.x, acc[0], acc[1]);
        upadd(u1.y, acc[2], acc[3]);
        upadd(u1.z, acc[4], acc[5]);
        upadd(u1.w, acc[6], acc[7]);
    }

    // cross-quarter reduction: lanes c, c+16, c+32, c+48 hold partials of cols 8c..8c+7
#pragma unroll
    for (int j = 0; j < 8; ++j) {
        acc[j] += __shfl_xor(acc[j], 16);
        acc[j] += __shfl_xor(acc[j], 32);
    }

    if (q == 0) {
        float r = 1.0f / fmaxf((float)dg, 1.0f);
        uint4 o;
        o.x = ((unsigned)f2bf(acc[1] * r) << 16) | f2bf(acc[0] * r);
        o.y = ((unsigned)f2bf(acc[3] * r) << 16) | f2bf(acc[2] * r);
        o.z = ((unsigned)f2bf(acc[5] * r) << 16) | f2bf(acc[4] * r);
        o.w = ((unsigned)f2bf(acc[7] * r) << 16) | f2bf(acc[6] * r);
        mean4[(size_t)n * (MPITCH / 8) + c] = o;
    }
}

// ---------------- MFMA GEMM: out = [mean|x] @ Wt^T + bias (+relu) ----------------
// 256 thr = 4 waves; block computes 64 rows x 128 cols; K=256 in 4 chunks.
// meanb: bf16, row pitch MPITCH (interleaved in d_out). xin: bf16, pitch F.
// Aliasing-safe: block reads ONLY its own rows of meanb/xin; epilogue writes
// those same rows after all reads (ordered by __syncthreads within block).
template <bool RELU, bool OUT_BF16>
__global__ __launch_bounds__(256) void sage_gemm_mfma(
    const unsigned short* __restrict__ meanb,
    const unsigned short* __restrict__ xin,
    const unsigned short* __restrict__ wt,   // [128 cols][256 k] bf16
    const float* __restrict__ bias,
    float* __restrict__ outp, unsigned short* __restrict__ outb, int N)
{
    __shared__ unsigned short As[64][72];    // stride 144 B: 16B-aligned, conflict-free b128
    __shared__ unsigned short Bs[128][72];

    const int t = threadIdx.x;
    const int block_row = blockIdx.x * 64;
    const int lane = t & 63;
    const int w = t >> 6;
    const int m = lane & 15;
    const int kq = lane >> 4;

    f32x4 acc[8];
#pragma unroll
    for (int i = 0; i < 8; ++i) acc[i] = (f32x4){0.f, 0.f, 0.f, 0.f};

    for (int chunk = 0; chunk < 4; ++chunk) {
        const bool is_mean = (chunk < 2);
        const int kbase = (chunk & 1) * 64;

        // ---- A tile: 64 rows x 64 k (each thread: 16 bf16 = 32 B) ----
        {
            int row_l = t >> 2;
            int seg = t & 3;
            int grow = block_row + row_l;
            unsigned short* dstp = &As[row_l][seg * 16];
            if (grow < N) {
                const unsigned short* srcp = is_mean
                    ? meanb + (size_t)grow * MPITCH + kbase + seg * 16
                    : xin   + (size_t)grow * F      + kbase + seg * 16;
                const uint4* p = (const uint4*)srcp;
                ((uint4*)dstp)[0] = p[0];
                ((uint4*)dstp)[1] = p[1];
            } else {
                uint4 z = make_uint4(0, 0, 0, 0);
                ((uint4*)dstp)[0] = z;
                ((uint4*)dstp)[1] = z;
            }
        }
        // ---- B tile: 128 cols x 64 k from Wt (each thread: 32 bf16 = 64 B) ----
        {
            int c = t >> 1;
            int half = t & 1;
            const uint4* p = (const uint4*)(wt + c * 256 + chunk * 64 + half * 32);
            unsigned short* dstp = &Bs[c][half * 32];
            ((uint4*)dstp)[0] = p[0];
            ((uint4*)dstp)[1] = p[1];
            ((uint4*)dstp)[2] = p[2];
            ((uint4*)dstp)[3] = p[3];
        }
        __syncthreads();

        // ---- MFMA: A[m=lane&15][k=(lane>>4)*8+j], B[k][n=lane&15] ----
#pragma unroll
        for (int ks = 0; ks < 2; ++ks) {
            short8 a = *(const short8*)&As[w * 16 + m][ks * 32 + kq * 8];
#pragma unroll
            for (int tt = 0; tt < 8; ++tt) {
                short8 b = *(const short8*)&Bs[tt * 16 + m][ks * 32 + kq * 8];
                acc[tt] = __builtin_amdgcn_mfma_f32_16x16x32_bf16(a, b, acc[tt], 0, 0, 0);
            }
        }
        __syncthreads();
    }

    // ---- epilogue: C/D row=(lane>>4)*4+reg, col=lane&15 ----
    float bb[8];
#pragma unroll
    for (int tt = 0; tt < 8; ++tt) bb[tt] = bias[tt * 16 + m];
    int rbase = block_row + w * 16 + kq * 4;
#pragma unroll
    for (int r = 0; r < 4; ++r) {
        int grow = rbase + r;
        if (grow < N) {
#pragma unroll
            for (int tt = 0; tt < 8; ++tt) {
                float v = acc[tt][r] + bb[tt];
                if (RELU) v = fmaxf(v, 0.f);
                if (OUT_BF16)
                    outb[(size_t)grow * F + tt * 16 + m] = f2bf(v);
                else
                    outp[(size_t)grow * F + tt * 16 + m] = v;
            }
        }
    }
}

extern "C" void kernel_launch(void* const* d_in, const int* in_sizes, int n_in,
                              void* d_out, int out_size, void* d_ws, size_t ws_size,
                              hipStream_t stream) {
    const float* x    = (const float*)d_in[0];
    const int*   ei   = (const int*)d_in[1];    // int32 (harness converts int64)
    const float* W_l1 = (const float*)d_in[2];
    const float* W_r1 = (const float*)d_in[3];
    const float* b1   = (const float*)d_in[4];
    const float* W_l2 = (const float*)d_in[5];
    const float* W_r2 = (const float*)d_in[6];
    const float* b2   = (const float*)d_in[7];
    float* out        = (float*)d_out;

    const int N = N_NODES;
    const int E = N_EDGES;
    const int* srcv = ei;
    const int* dstv = ei + E;

    // ---- workspace layout (bytes); ws_size proven >= 33,337,344 ----
    const size_t rowptr_off = 400128;
    const size_t part_off   = 800256;            // 2048 B
    const size_t csr_off    = 802304;            // int[1.6M] = 6.4 MB
    const size_t xb_off     = 7202304;           // bf16[N*F] = 25.6 MB -> 32,802,304
    const size_t wt_off     = 32802304;          // bf16[2][128][256] -> 32,933,376
    const size_t need_min   = 32933376;          // < proven 33,337,344
    // transients aliased into xb region (consumed by bucket_fill before cast):
    const size_t blkh_rel   = 0;                 // int[NSB*NBK]
    const size_t bbase_rel  = 1223168;           // int[NSB*NBK]
    const size_t stag_rel   = 2446336;           // uint[1.6M] -> 8,846,336 (< 25.6MB)

    if (ws_size < need_min) return;  // clean validation failure as diagnostic

    char* ws = (char*)d_ws;
    int* deg_i   = (int*)ws;
    int* rowptr  = (int*)(ws + rowptr_off);
    int* partial = (int*)(ws + part_off);
    int* csr_src = (int*)(ws + csr_off);
    unsigned short* xb = (unsigned short*)(ws + xb_off);
    int* blkhist = (int*)(ws + xb_off + blkh_rel);
    int* bbase   = (int*)(ws + xb_off + bbase_rel);
    unsigned* staging = (unsigned*)(ws + xb_off + stag_rel);
    unsigned short* wt = (unsigned short*)(ws + wt_off);
    // means live interleaved in d_out: row n -> bytes [n*512, n*512+256)
    uint4* mean4 = (uint4*)d_out;
    const unsigned short* meanb = (const unsigned short*)d_out;

    // ---- deg + rowptr ----
    hipMemsetAsync(deg_i, 0, (size_t)N * sizeof(int), stream);
    hist_kernel<<<dim3((E + 255) / 256), dim3(256), 0, stream>>>(dstv, deg_i, E);
    partial_sum_kernel<<<dim3(NB), dim3(256), 0, stream>>>(deg_i, partial, N);
    scan_partial_kernel<<<dim3(1), dim3(512), 0, stream>>>(partial);
    rowptr_kernel<<<dim3(NB), dim3(256), 0, stream>>>(deg_i, partial, rowptr, N);

    // ---- contention-free bucket permute -> csr_src ----
    blkhist_kernel<<<dim3(NSB), dim3(256), 0, stream>>>(dstv, blkhist, E);
    bucket_scan_kernel<<<dim3(NBK), dim3(512), 0, stream>>>(blkhist, rowptr, bbase);
    bucket_scatter_kernel<<<dim3(NSB), dim3(256), 0, stream>>>(
        srcv, dstv, bbase, staging, E);
    bucket_fill_kernel<<<dim3(NBK), dim3(256), 0, stream>>>(
        staging, rowptr, csr_src, N, E);

    // ---- weight prep + x cast (after staging consumed) ----
    wt_kernel<<<dim3(256), dim3(256), 0, stream>>>(W_l1, W_r1, W_l2, W_r2, wt);
    cast_kernel<<<dim3((N * F / 4 + 255) / 256), dim3(256), 0, stream>>>(x, xb, N * F / 4);

    dim3 ablock(256), agrid((N + 3) / 4);
    dim3 gblock(256), ggrid((N + 63) / 64);

    // ---- layer 1: mean1(xb) -> d_out interleaved; gemm1 -> h bf16 into xb ----
    csr_mean_kernel<<<agrid, ablock, 0, stream>>>(
        (const uint4*)xb, rowptr, deg_i, csr_src, mean4, N);
    sage_gemm_mfma<true, true><<<ggrid, gblock, 0, stream>>>(
        meanb, xb, wt, b1, nullptr, xb, N);

    // ---- layer 2: mean2(xb=h) -> d_out interleaved; gemm2 -> fp32 d_out ----
    csr_mean_kernel<<<agrid, ablock, 0, stream>>>(
        (const uint4*)xb, rowptr, deg_i, csr_src, mean4, N);
    sage_gemm_mfma<false, false><<<ggrid, gblock, 0, stream>>>(
        meanb, xb, wt + 32768, b2, out, nullptr, N);
}